// Round 9
// baseline (273.593 us; speedup 1.0000x reference)
//
#include <hip/hip_runtime.h>

#define EPS 1e-5f

namespace {
constexpr int HYPER = 14016;
constexpr int HID   = 192;
constexpr int A1    = 324;   // 18*18
constexpr int A2    = 256;   // 16*16
constexpr int P_TOT = 512;
constexpr int W1SZ  = 6144;  // 32*192
constexpr int WT2SZ = 7872;  // w2 (1728) + w3 (6144)
constexpr int R3OFF = 1728;  // w3 offset inside wt2

// workspace byte offsets
constexpr size_t WB1_B = 0;                       // bf16 w1 A-frag order [p][6144], 6,291,456 B
constexpr size_t WT2_B = 6291456;                 // fp32 w2+w3 [p][7872], 16,121,856 B
constexpr size_t X2_B  = WT2_B + 16121856;        // bf16 x2 [p][12][256][16], 50,331,648 B
constexpr size_t X3_B  = X2_B + 50331648;         // bf16 x3 [p][32][256], 8,388,608 B
constexpr size_t SUM_B = X3_B + 8388608;          // fp32 832 floats
// sums: [0:192) s1 [192:384) q1 [384:576) s2 [576:768) q2 [768:800) s3 [800:832) q3
}

typedef __attribute__((ext_vector_type(8))) short bf16x8;
typedef __attribute__((ext_vector_type(4))) float f32x4;

__device__ __forceinline__ float relu6f(float v) { return fminf(fmaxf(v, 0.f), 6.f); }

__device__ __forceinline__ float bf2f(unsigned int h) {
  return __uint_as_float(h << 16);
}
__device__ __forceinline__ unsigned short f2bf(float f) {
  unsigned int u = __float_as_uint(f);
  return (unsigned short)((u + 0x7FFFu + ((u >> 16) & 1u)) >> 16);
}

// A-frag slot for element w1[o][c] (o<192, c<32), 16x16x32 MFMA:
// lane = (c>>3)*16 + (o&15), j = c&7  ->  slot = (o>>4)*512 + lane*8 + j
__device__ __host__ __forceinline__ int afrag_slot(int o, int c) {
  return (o >> 4) * 512 + (c >> 3) * 128 + (o & 15) * 8 + (c & 7);
}

// ---------------- K0: transpose s; w1 -> bf16 wb1 (A-frag order), rest -> fp32 wt2 ----------------
__global__ __launch_bounds__(256) void k0_transpose(const float* __restrict__ s,
                                                    unsigned short* __restrict__ wb1,
                                                    float* __restrict__ wt2) {
  __shared__ float tile[64][65];
  const int blk = blockIdx.x;            // b*219 + kt
  const int b  = blk / 219;
  const int kt = blk - b * 219;
  const int k0 = kt * 64;
  const int t  = threadIdx.x;
  {
    const int f  = t & 63;
    const int kr = t >> 6;
    const float* sp = s + ((size_t)b * HYPER + k0 + kr) * 64 + f;
#pragma unroll
    for (int kk = 0; kk < 16; kk++)
      tile[kr + kk * 4][f] = sp[(size_t)kk * 4 * 64];
  }
  __syncthreads();
  {
    const int kk = t & 63;
    const int fr = t >> 6;
    if (kt < 96) {   // w1 region (k < 6144): emit bf16 in A-frag order
      const int k = k0 + kk;
      const int o = k >> 5, c = k & 31;
      const int slot = afrag_slot(o, c);
      unsigned short* wp = wb1 + ((size_t)b * 64 + fr) * W1SZ + slot;
#pragma unroll
      for (int ff = 0; ff < 16; ff++)
        wp[(size_t)ff * 4 * W1SZ] = f2bf(tile[kk][fr + ff * 4]);
    } else {
      float* wp = wt2 + ((size_t)b * 64 + fr) * WT2SZ + (k0 - W1SZ) + kk;
#pragma unroll
      for (int ff = 0; ff < 16; ff++)
        wp[(size_t)ff * 4 * WT2SZ] = tile[kk][fr + ff * 4];
    }
  }
}

// ---------------- K1: MFMA conv1, bn1 stats ONLY (no x1 materialization) ----------------
__global__ __launch_bounds__(256) void k1_stats(const float* __restrict__ x,
                                                const unsigned short* __restrict__ wb1,
                                                float* __restrict__ sums) {
  __shared__ __align__(16) unsigned short pL[21 * 512];   // B frags: 21 ij-tiles
  __shared__ float stat[384];
  const int p  = blockIdx.x;
  const int b  = p >> 6;
  const int fi = (p >> 3) & 7;
  const int fj = p & 7;
  const int t  = threadIdx.x;

  for (int i = t; i < 384; i += 256) stat[i] = 0.f;

  // stage patch frags: value B[c][ij] = patch[ij][c] (reflect-pad gather)
  const int row0 = fi * 16 - 1, col0 = fj * 16 - 1;
  const float* xb = x + (size_t)b * 32 * 128 * 128;
  for (int idx = t; idx < 32 * A1; idx += 256) {
    int c  = idx / A1;
    int ij = idx - c * A1;
    int ii = ij / 18;
    int jj = ij - ii * 18;
    int r  = row0 + ii; r  = (r  < 0) ? 1 : (r  > 127) ? 126 : r;
    int cl = col0 + jj; cl = (cl < 0) ? 1 : (cl > 127) ? 126 : cl;
    int slot = ((ij >> 4) * 4 + (c >> 3)) * 128 + (ij & 15) * 8 + (c & 7);
    pL[slot] = f2bf(xb[((size_t)c * 128 + r) * 128 + cl]);
  }
  __syncthreads();

  const int lane = t & 63;
  const int wv   = t >> 6;
  const int m16  = lane & 15;
  const int quad = lane >> 4;
  const unsigned short* wbp = wb1 + (size_t)p * W1SZ;

  for (int oi = 0; oi < 3; oi++) {
    const int ot = wv + oi * 4;                       // 0..11 across 4 waves
    bf16x8 a = *(const bf16x8*)(wbp + ot * 512 + lane * 8);   // pre-swizzled global
    float sacc[4] = {0.f, 0.f, 0.f, 0.f};
    float qacc[4] = {0.f, 0.f, 0.f, 0.f};
    for (int jt = 0; jt < 21; jt++) {
      bf16x8 bb = *(const bf16x8*)&pL[jt * 512 + lane * 8];
      f32x4 d = __builtin_amdgcn_mfma_f32_16x16x32_bf16(a, bb, (f32x4){0.f, 0.f, 0.f, 0.f}, 0, 0, 0);
      const int ij = jt * 16 + m16;                   // D col = lane&15
      if (ij < A1) {
#pragma unroll
        for (int r = 0; r < 4; r++) {                 // D row = quad*4 + r
          float v = d[r];                             // raw fp32 (k2 recomputes same)
          sacc[r] += v;
          qacc[r] = fmaf(v, v, qacc[r]);
        }
      }
    }
#pragma unroll
    for (int r = 0; r < 4; r++) {
      float sv = sacc[r], qv = qacc[r];
#pragma unroll
      for (int msk = 1; msk < 16; msk <<= 1) {
        sv += __shfl_xor(sv, msk, 64);
        qv += __shfl_xor(qv, msk, 64);
      }
      if (m16 == 0) {
        int o = ot * 16 + quad * 4 + r;
        atomicAdd(&stat[o], sv);
        atomicAdd(&stat[192 + o], qv);
      }
    }
  }
  __syncthreads();
  for (int i = t; i < 384; i += 256) atomicAdd(&sums[i], stat[i]);
}

// ---------------- K2: fused conv1-recompute + bn1 + relu6 + depthwise 3x3 + bn2 stats ----
// grid: 6144 = patch(512) * o-tile(12); one 16-channel tile per block, 3 barriers total.
// x2 layout [p][12 ot][256 ij][16 c] bf16.
__global__ __launch_bounds__(256) void k2_fused(const float* __restrict__ x,
                                                const unsigned short* __restrict__ wb1,
                                                const float* __restrict__ wt2,
                                                const float* __restrict__ sums,
                                                const float* __restrict__ g1,
                                                const float* __restrict__ b1,
                                                unsigned short* __restrict__ x2,
                                                float* __restrict__ sums2) {
  __shared__ __align__(16) unsigned short pL[21 * 512];      // 21504 B
  __shared__ __align__(16) unsigned short xc[16 * 328];      // 10496 B [c][ij pad]
  __shared__ __align__(16) unsigned short x2s[256 * 18];     //  9216 B [ij][16 + 2 pad]
  __shared__ float w2L[16 * 9];                              //   576 B
  __shared__ float scc[16], shc[16];                         //   128 B
  __shared__ float st2[32];                                  //   128 B => ~42 KB total
  const int blk = blockIdx.x;
  const int p   = blk / 12;
  const int rt  = blk - p * 12;
  const int b  = p >> 6;
  const int fi = (p >> 3) & 7;
  const int fj = p & 7;
  const int t  = threadIdx.x;

  const float inv1 = 1.f / 165888.f;    // 512*324
  if (t < 16) {
    int c = rt * 16 + t;
    float m   = sums[c] * inv1;
    float var = sums[192 + c] * inv1 - m * m;
    float scl = g1[c] * rsqrtf(var + EPS);
    scc[t] = scl;
    shc[t] = b1[c] - m * scl;
  }
  if (t < 32) st2[t] = 0.f;
  if (t >= 32 && t < 32 + 144) {
    int i = t - 32;
    w2L[i] = wt2[(size_t)p * WT2SZ + rt * 144 + i];
  }

  // stage patch B-frags (full 32 input channels; identical to k1)
  const int row0 = fi * 16 - 1, col0 = fj * 16 - 1;
  const float* xb = x + (size_t)b * 32 * 128 * 128;
  for (int idx = t; idx < 32 * A1; idx += 256) {
    int c  = idx / A1;
    int ij = idx - c * A1;
    int ii = ij / 18;
    int jj = ij - ii * 18;
    int r  = row0 + ii; r  = (r  < 0) ? 1 : (r  > 127) ? 126 : r;
    int cl = col0 + jj; cl = (cl < 0) ? 1 : (cl > 127) ? 126 : cl;
    int slot = ((ij >> 4) * 4 + (c >> 3)) * 128 + (ij & 15) * 8 + (c & 7);
    pL[slot] = f2bf(xb[((size_t)c * 128 + r) * 128 + cl]);
  }
  __syncthreads();

  const int lane = t & 63;
  const int wv   = t >> 6;
  const int m16  = lane & 15;
  const int quad = lane >> 4;

  // ---- conv1 for tile rt: 4 waves split the 21 jt; bn1+relu6 -> xc[c][ij] ----
  {
    bf16x8 a = *(const bf16x8*)(wb1 + (size_t)p * W1SZ + rt * 512 + lane * 8);
    for (int jt = wv; jt < 21; jt += 4) {
      bf16x8 bb = *(const bf16x8*)&pL[jt * 512 + lane * 8];
      f32x4 d = __builtin_amdgcn_mfma_f32_16x16x32_bf16(a, bb, (f32x4){0.f, 0.f, 0.f, 0.f}, 0, 0, 0);
      const int ij = jt * 16 + m16;
      if (ij < A1) {
#pragma unroll
        for (int r = 0; r < 4; r++) {
          int cl = quad * 4 + r;
          float v = relu6f(fmaf(d[r], scc[cl], shc[cl]));
          xc[cl * 328 + ij] = f2bf(v);
        }
      }
    }
  }
  __syncthreads();

  // ---- depthwise: thread = (ih, cdw, jp); aligned b32 LDS reads ----
  {
    const int ih  = t >> 7;          // 0..1  (i-half)
    const int cdw = (t >> 3) & 15;   // 0..15 (channel within tile)
    const int jp  = t & 7;           // 0..7  (j-pair)
    float wr[9];
#pragma unroll
    for (int u = 0; u < 9; u++) wr[u] = w2L[cdw * 9 + u];
    float a0[8], a1[8];
#pragma unroll
    for (int i = 0; i < 8; i++) { a0[i] = 0.f; a1[i] = 0.f; }
    const unsigned short* xcc = &xc[cdw * 328];
#pragma unroll
    for (int rr = 0; rr < 10; rr++) {
      const int rg = ih * 8 + rr;
      unsigned int d0 = *(const unsigned int*)&xcc[rg * 18 + jp * 2];
      unsigned int d1 = *(const unsigned int*)&xcc[rg * 18 + jp * 2 + 2];
      float v0 = bf2f(d0 & 0xFFFFu), v1 = bf2f(d0 >> 16);
      float v2 = bf2f(d1 & 0xFFFFu), v3 = bf2f(d1 >> 16);
#pragma unroll
      for (int u = 0; u < 3; u++) {
        int il = rr - u;
        if (il >= 0 && il < 8) {
          a0[il] = fmaf(v0, wr[u * 3 + 0], fmaf(v1, wr[u * 3 + 1], fmaf(v2, wr[u * 3 + 2], a0[il])));
          a1[il] = fmaf(v1, wr[u * 3 + 0], fmaf(v2, wr[u * 3 + 1], fmaf(v3, wr[u * 3 + 2], a1[il])));
        }
      }
    }
    float ls = 0.f, lq = 0.f;
#pragma unroll
    for (int il = 0; il < 8; il++) {
      const int ig = ih * 8 + il;
      const int j0 = jp * 2;
      unsigned short h0 = f2bf(a0[il]);
      unsigned short h1 = f2bf(a1[il]);
      float r0 = bf2f(h0), r1 = bf2f(h1);
      ls += r0 + r1;
      lq = fmaf(r0, r0, fmaf(r1, r1, lq));
      x2s[(ig * 16 + j0) * 18 + cdw]     = h0;
      x2s[(ig * 16 + j0 + 1) * 18 + cdw] = h1;
    }
    // reduce over jp (lanes cdw*8+jp within wave)
    ls += __shfl_xor(ls, 1, 64); lq += __shfl_xor(lq, 1, 64);
    ls += __shfl_xor(ls, 2, 64); lq += __shfl_xor(lq, 2, 64);
    ls += __shfl_xor(ls, 4, 64); lq += __shfl_xor(lq, 4, 64);
    if (jp == 0) {
      atomicAdd(&st2[cdw], ls);
      atomicAdd(&st2[16 + cdw], lq);
    }
  }
  __syncthreads();

  // ---- coop store x2s -> global [p][rt][256][16]; stats to global ----
  {
    unsigned short* dst = x2 + (size_t)p * 12 * 4096 + (size_t)rt * 4096;
#pragma unroll
    for (int k = 0; k < 4; k++) {
      int g  = (k * 256 + t) * 4;          // ushort offset, multiple of 4
      int ij = g >> 4, c0 = g & 15;
      unsigned int v0 = *(const unsigned int*)&x2s[ij * 18 + c0];
      unsigned int v1 = *(const unsigned int*)&x2s[ij * 18 + c0 + 2];
      uint2 v; v.x = v0; v.y = v1;
      *(uint2*)&dst[g] = v;
    }
  }
  if (t < 16)      atomicAdd(&sums2[rt * 16 + t], st2[t]);
  else if (t < 32) atomicAdd(&sums2[192 + rt * 16 + (t - 16)], st2[t]);
}

// ---------------- K3: MFMA pointwise 192->32, bn2+relu6 fused on B-load ----------------
// grid: 1024 = patch(512) * ij-half(2); x3 bf16 [p][o][256]; bn3 stats (on rounded values)
__global__ __launch_bounds__(256) void k3_pw2(const unsigned short* __restrict__ x2,
                                              const float* __restrict__ wt2,
                                              const float* __restrict__ sums2,
                                              const float* __restrict__ g2,
                                              const float* __restrict__ b2,
                                              unsigned short* __restrict__ x3,
                                              float* __restrict__ sums3) {
  __shared__ __align__(16) unsigned short wA[12 * 512];   // A frags: [ot(2)][ks(6)]
  __shared__ float sc[HID], sh[HID];
  __shared__ float st3[64];
  const int blk  = blockIdx.x;
  const int p    = blk >> 1;
  const int half = blk & 1;
  const int t    = threadIdx.x;
  const float inv = 1.f / 131072.f;   // 512*256
  for (int c = t; c < HID; c += 256) {
    float m   = sums2[c] * inv;
    float var = sums2[192 + c] * inv - m * m;
    float scl = g2[c] * rsqrtf(var + EPS);
    sc[c] = scl;
    sh[c] = b2[c] - m * scl;
  }
  if (t < 64) st3[t] = 0.f;
  // stage w3 -> bf16 A-frags: A[m=o&15][k], frag (ot=o>>4, ks=c>>5)
  const float* w3p = wt2 + (size_t)p * WT2SZ + R3OFF;     // [o][192]
  for (int idx = t; idx < 32 * 48; idx += 256) {
    int o  = idx / 48;
    int c4 = idx - o * 48;
    float4 v = *(const float4*)&w3p[o * HID + c4 * 4];
    int slot = ((o >> 4) * 6 + (c4 >> 3)) * 512 + ((((c4 >> 1) & 3) * 16) + (o & 15)) * 8 + (c4 & 1) * 4;
    ushort4 u;
    u.x = f2bf(v.x); u.y = f2bf(v.y); u.z = f2bf(v.z); u.w = f2bf(v.w);
    *(ushort4*)&wA[slot] = u;
  }
  __syncthreads();
  const int lane = t & 63;
  const int wv   = t >> 6;
  const int m16  = lane & 15;
  const int kg   = lane >> 4;
  bf16x8 aF[2][6];
#pragma unroll
  for (int ot = 0; ot < 2; ot++)
#pragma unroll
    for (int ks = 0; ks < 6; ks++)
      aF[ot][ks] = *(const bf16x8*)&wA[(ot * 6 + ks) * 512 + lane * 8];
  const unsigned short* x2p = x2 + (size_t)p * 12 * 4096;
  f32x4 acc[2][2];
#pragma unroll
  for (int it = 0; it < 2; it++)
#pragma unroll
    for (int ot = 0; ot < 2; ot++)
#pragma unroll
      for (int r = 0; r < 4; r++) acc[it][ot][r] = 0.f;
#pragma unroll
  for (int it = 0; it < 2; it++) {
    const int ijt = half * 8 + wv + it * 4;
    const int ij  = ijt * 16 + m16;
    // x2 [ot12][ij][16]: for k = ks*32 + kg*8 + j, addr = ks*8192 + (kg>>1)*4096 + ij*16 + (kg&1)*8
    const unsigned short* brow = x2p + (size_t)(kg >> 1) * 4096 + (size_t)ij * 16 + (kg & 1) * 8;
#pragma unroll
    for (int ks = 0; ks < 6; ks++) {
      ushort4 u0 = *(const ushort4*)&brow[ks * 8192];
      ushort4 u1 = *(const ushort4*)&brow[ks * 8192 + 4];
      const float* scp = &sc[ks * 32 + kg * 8];
      const float* shp = &sh[ks * 32 + kg * 8];
      unsigned short uu[8] = {u0.x, u0.y, u0.z, u0.w, u1.x, u1.y, u1.z, u1.w};
      bf16x8 bb;
#pragma unroll
      for (int j = 0; j < 8; j++) {
        float y = relu6f(fmaf(bf2f(uu[j]), scp[j], shp[j]));
        bb[j] = (short)f2bf(y);
      }
      acc[it][0] = __builtin_amdgcn_mfma_f32_16x16x32_bf16(aF[0][ks], bb, acc[it][0], 0, 0, 0);
      acc[it][1] = __builtin_amdgcn_mfma_f32_16x16x32_bf16(aF[1][ks], bb, acc[it][1], 0, 0, 0);
    }
  }
  unsigned short* x3p = x3 + (size_t)p * 32 * A2;
  float sacc[2][4] = {{0.f}}, qacc[2][4] = {{0.f}};
#pragma unroll
  for (int it = 0; it < 2; it++) {
    const int ijt = half * 8 + wv + it * 4;
#pragma unroll
    for (int ot = 0; ot < 2; ot++) {
#pragma unroll
      for (int r = 0; r < 4; r++) {
        unsigned short h = f2bf(acc[it][ot][r]);
        float v = bf2f(h);
        x3p[(size_t)(ot * 16 + kg * 4 + r) * A2 + ijt * 16 + m16] = h;
        sacc[ot][r] += v;
        qacc[ot][r] = fmaf(v, v, qacc[ot][r]);
      }
    }
  }
#pragma unroll
  for (int ot = 0; ot < 2; ot++)
#pragma unroll
    for (int r = 0; r < 4; r++) {
      float sv = sacc[ot][r], qv = qacc[ot][r];
#pragma unroll
      for (int msk = 1; msk < 16; msk <<= 1) {
        sv += __shfl_xor(sv, msk, 64);
        qv += __shfl_xor(qv, msk, 64);
      }
      if (m16 == 0) {
        int o = ot * 16 + kg * 4 + r;
        atomicAdd(&st3[o], sv);
        atomicAdd(&st3[32 + o], qv);
      }
    }
  __syncthreads();
  if (t < 64) atomicAdd(&sums3[t], st3[t]);
}

// ---------------- K4: bn3 + residual + layout transform ----------------
__global__ __launch_bounds__(256) void k4_out(const float* __restrict__ x,
                                              const unsigned short* __restrict__ x3,
                                              const float* __restrict__ sums3,
                                              const float* __restrict__ g3,
                                              const float* __restrict__ b3,
                                              float* __restrict__ out) {
  const int idx4 = blockIdx.x * 256 + threadIdx.x;   // 1,048,576 float4 total
  const int w4 = idx4 & 31;
  int tmp = idx4 >> 5;
  const int h = tmp & 127; tmp >>= 7;
  const int o = tmp & 31;
  const int b = tmp >> 5;
  const int fi = h >> 4, i = h & 15;
  const int fj = w4 >> 2;
  const int j0 = (w4 & 3) * 4;
  const int p   = b * 64 + fi * 8 + fj;
  const int ij0 = i * 16 + j0;
  const float inv = 1.f / 131072.f;
  float m   = sums3[o] * inv;
  float var = sums3[32 + o] * inv - m * m;
  float sv  = g3[o] * rsqrtf(var + EPS);
  float shv = b3[o] - m * sv;
  float4 xv = *(const float4*)&x[(size_t)idx4 * 4];
  ushort4 u = *(const ushort4*)&x3[((size_t)p * 32 + o) * A2 + ij0];
  float4 r;
  r.x = fmaf(bf2f(u.x), sv, shv) + xv.x;
  r.y = fmaf(bf2f(u.y), sv, shv) + xv.y;
  r.z = fmaf(bf2f(u.z), sv, shv) + xv.z;
  r.w = fmaf(bf2f(u.w), sv, shv) + xv.w;
  *(float4*)&out[(size_t)idx4 * 4] = r;
}

extern "C" void kernel_launch(void* const* d_in, const int* in_sizes, int n_in,
                              void* d_out, int out_size, void* d_ws, size_t ws_size,
                              hipStream_t stream) {
  const float* x  = (const float*)d_in[0];
  const float* s  = (const float*)d_in[1];
  const float* g1 = (const float*)d_in[2];
  const float* b1 = (const float*)d_in[3];
  const float* g2 = (const float*)d_in[4];
  const float* b2 = (const float*)d_in[5];
  const float* g3 = (const float*)d_in[6];
  const float* b3 = (const float*)d_in[7];
  char* base = (char*)d_ws;
  unsigned short* wb1  = (unsigned short*)(base + WB1_B);
  float*          wt2  = (float*)(base + WT2_B);
  unsigned short* x2   = (unsigned short*)(base + X2_B);
  unsigned short* x3   = (unsigned short*)(base + X3_B);
  float*          sums = (float*)(base + SUM_B);
  float* out = (float*)d_out;

  hipMemsetAsync(sums, 0, 832 * sizeof(float), stream);
  k0_transpose<<<8 * 219, 256, 0, stream>>>(s, wb1, wt2);
  k1_stats<<<P_TOT, 256, 0, stream>>>(x, wb1, sums);
  k2_fused<<<P_TOT * 12, 256, 0, stream>>>(x, wb1, wt2, sums, g1, b1, x2, sums + 384);
  k3_pw2<<<1024, 256, 0, stream>>>(x2, wt2, sums + 384, g2, b2, x3, sums + 768);
  k4_out<<<4096, 256, 0, stream>>>(x, x3, sums + 768, g3, b3, out);
}

// Round 10
// 224.756 us; speedup vs baseline: 1.2173x; 1.2173x over previous
//
#include <hip/hip_runtime.h>

#define EPS 1e-5f

namespace {
constexpr int HYPER = 14016;
constexpr int HID   = 192;
constexpr int A1    = 324;   // 18*18
constexpr int A2    = 256;   // 16*16
constexpr int P_TOT = 512;
constexpr int W1SZ  = 6144;  // 32*192
constexpr int WT2SZ = 7872;  // w2 (1728) + w3 (6144)
constexpr int R3OFF = 1728;  // w3 offset inside wt2

// workspace byte offsets
constexpr size_t WB1_B = 0;                       // bf16 w1 A-frag order [p][6144], 6,291,456 B
constexpr size_t WT2_B = 6291456;                 // fp32 w2+w3 [p][7872], 16,121,856 B
constexpr size_t X2_B  = WT2_B + 16121856;        // bf16 x2 [p][12][256][16], 50,331,648 B
constexpr size_t X3_B  = X2_B + 50331648;         // bf16 x3 [p][32][256], 8,388,608 B
constexpr size_t SUM_B = X3_B + 8388608;          // fp32 832 floats
// sums: [0:192) s1 [192:384) q1 [384:576) s2 [576:768) q2 [768:800) s3 [800:832) q3
}

typedef __attribute__((ext_vector_type(8))) short bf16x8;
typedef __attribute__((ext_vector_type(4))) float f32x4;

__device__ __forceinline__ float relu6f(float v) { return fminf(fmaxf(v, 0.f), 6.f); }

__device__ __forceinline__ float bf2f(unsigned int h) {
  return __uint_as_float(h << 16);
}
__device__ __forceinline__ unsigned short f2bf(float f) {
  unsigned int u = __float_as_uint(f);
  return (unsigned short)((u + 0x7FFFu + ((u >> 16) & 1u)) >> 16);
}

// A-frag slot for element w1[o][c] (o<192, c<32), 16x16x32 MFMA:
// lane = (c>>3)*16 + (o&15), j = c&7  ->  slot = (o>>4)*512 + lane*8 + j
__device__ __host__ __forceinline__ int afrag_slot(int o, int c) {
  return (o >> 4) * 512 + (c >> 3) * 128 + (o & 15) * 8 + (c & 7);
}

// ---------------- K0: transpose s; w1 -> bf16 wb1 (A-frag order), rest -> fp32 wt2 ----
// Phase 2 rewritten for COALESCED writes: 16B dwordx4 stores instead of 2B/4B scatter.
__global__ __launch_bounds__(256) void k0_transpose(const float* __restrict__ s,
                                                    unsigned short* __restrict__ wb1,
                                                    float* __restrict__ wt2) {
  __shared__ float tile[64][65];
  const int blk = blockIdx.x;            // b*219 + kt
  const int b  = blk / 219;
  const int kt = blk - b * 219;
  const int k0 = kt * 64;
  const int t  = threadIdx.x;
  {
    const int f  = t & 63;
    const int kr = t >> 6;
    const float* sp = s + ((size_t)b * HYPER + k0 + kr) * 64 + f;
#pragma unroll
    for (int kk = 0; kk < 16; kk++)
      tile[kr + kk * 4][f] = sp[(size_t)kk * 4 * 64];
  }
  __syncthreads();
  if (kt < 96) {
    // w1 region: 64 k = 2 o-values x 32 c. Runs of 8 consecutive c are 16B-contiguous
    // in A-frag order. 512 runs per block -> 2 per thread, one dwordx4 store each.
    const int o0 = kt * 2;
#pragma unroll
    for (int rr = 0; rr < 2; rr++) {
      const int run = rr * 256 + t;          // f(64) x o1(2) x c4(4)
      const int f   = run >> 3;
      const int o1  = (run >> 2) & 1;
      const int c4  = run & 3;
      const int o   = o0 + o1;
      unsigned int pk[4];
#pragma unroll
      for (int e4 = 0; e4 < 4; e4++) {
        unsigned int lo = f2bf(tile[o1 * 32 + c4 * 8 + e4 * 2][f]);
        unsigned int hi = f2bf(tile[o1 * 32 + c4 * 8 + e4 * 2 + 1][f]);
        pk[e4] = lo | (hi << 16);
      }
      unsigned short* wp = wb1 + ((size_t)b * 64 + f) * W1SZ
                         + (o >> 4) * 512 + c4 * 128 + (o & 15) * 8;
      uint4 v; v.x = pk[0]; v.y = pk[1]; v.z = pk[2]; v.w = pk[3];
      *(uint4*)wp = v;
    }
  } else {
    // wt2 region: output rows are contiguous in k. Thread = (f, kq): 16 floats
    // = 4 float4 stores.
    const int f  = t >> 2;
    const int kq = t & 3;
    float* wp = wt2 + ((size_t)b * 64 + f) * WT2SZ + (k0 - W1SZ) + kq * 16;
#pragma unroll
    for (int q = 0; q < 4; q++) {
      float4 v;
      v.x = tile[kq * 16 + q * 4 + 0][f];
      v.y = tile[kq * 16 + q * 4 + 1][f];
      v.z = tile[kq * 16 + q * 4 + 2][f];
      v.w = tile[kq * 16 + q * 4 + 3][f];
      *(float4*)(wp + q * 4) = v;
    }
  }
}

// ---------------- K1: MFMA conv1, bn1 stats ONLY (no x1 materialization) ----------------
__global__ __launch_bounds__(256) void k1_stats(const float* __restrict__ x,
                                                const unsigned short* __restrict__ wb1,
                                                float* __restrict__ sums) {
  __shared__ __align__(16) unsigned short pL[21 * 512];   // B frags: 21 ij-tiles
  __shared__ float stat[384];
  const int p  = blockIdx.x;
  const int b  = p >> 6;
  const int fi = (p >> 3) & 7;
  const int fj = p & 7;
  const int t  = threadIdx.x;

  for (int i = t; i < 384; i += 256) stat[i] = 0.f;

  // stage patch frags: value B[c][ij] = patch[ij][c] (reflect-pad gather)
  const int row0 = fi * 16 - 1, col0 = fj * 16 - 1;
  const float* xb = x + (size_t)b * 32 * 128 * 128;
  for (int idx = t; idx < 32 * A1; idx += 256) {
    int c  = idx / A1;
    int ij = idx - c * A1;
    int ii = ij / 18;
    int jj = ij - ii * 18;
    int r  = row0 + ii; r  = (r  < 0) ? 1 : (r  > 127) ? 126 : r;
    int cl = col0 + jj; cl = (cl < 0) ? 1 : (cl > 127) ? 126 : cl;
    int slot = ((ij >> 4) * 4 + (c >> 3)) * 128 + (ij & 15) * 8 + (c & 7);
    pL[slot] = f2bf(xb[((size_t)c * 128 + r) * 128 + cl]);
  }
  __syncthreads();

  const int lane = t & 63;
  const int wv   = t >> 6;
  const int m16  = lane & 15;
  const int quad = lane >> 4;
  const unsigned short* wbp = wb1 + (size_t)p * W1SZ;

  for (int oi = 0; oi < 3; oi++) {
    const int ot = wv + oi * 4;                       // 0..11 across 4 waves
    bf16x8 a = *(const bf16x8*)(wbp + ot * 512 + lane * 8);   // pre-swizzled global
    float sacc[4] = {0.f, 0.f, 0.f, 0.f};
    float qacc[4] = {0.f, 0.f, 0.f, 0.f};
    for (int jt = 0; jt < 21; jt++) {
      bf16x8 bb = *(const bf16x8*)&pL[jt * 512 + lane * 8];
      f32x4 d = __builtin_amdgcn_mfma_f32_16x16x32_bf16(a, bb, (f32x4){0.f, 0.f, 0.f, 0.f}, 0, 0, 0);
      const int ij = jt * 16 + m16;                   // D col = lane&15
      if (ij < A1) {
#pragma unroll
        for (int r = 0; r < 4; r++) {                 // D row = quad*4 + r
          float v = d[r];                             // raw fp32 (k2 recomputes same)
          sacc[r] += v;
          qacc[r] = fmaf(v, v, qacc[r]);
        }
      }
    }
#pragma unroll
    for (int r = 0; r < 4; r++) {
      float sv = sacc[r], qv = qacc[r];
#pragma unroll
      for (int msk = 1; msk < 16; msk <<= 1) {
        sv += __shfl_xor(sv, msk, 64);
        qv += __shfl_xor(qv, msk, 64);
      }
      if (m16 == 0) {
        int o = ot * 16 + quad * 4 + r;
        atomicAdd(&stat[o], sv);
        atomicAdd(&stat[192 + o], qv);
      }
    }
  }
  __syncthreads();
  for (int i = t; i < 384; i += 256) atomicAdd(&sums[i], stat[i]);
}

// ---------------- K2: fused conv1-recompute + bn1 + relu6 + depthwise 3x3 + bn2 stats ----
// grid: 512 (one patch per block). x2 layout [p][12 ot][256 ij][16 c] bf16.
// 12 rounds x 1 o-tile; xc layout [c_local][ij pad 328] so dw reads are aligned b32.
__global__ __launch_bounds__(256) void k2_fused(const float* __restrict__ x,
                                                const unsigned short* __restrict__ wb1,
                                                const float* __restrict__ wt2,
                                                const float* __restrict__ sums,
                                                const float* __restrict__ g1,
                                                const float* __restrict__ b1,
                                                unsigned short* __restrict__ x2,
                                                float* __restrict__ sums2) {
  __shared__ __align__(16) unsigned short pL[21 * 512];      // 21504 B
  __shared__ __align__(16) unsigned short xc[16 * 328];      // 10496 B [c][ij pad]
  __shared__ __align__(16) unsigned short x2s[256 * 18];     //  9216 B [ij][16 + 2 pad]
  __shared__ float w2L[HID * 9];                             //  6912 B
  __shared__ float sc[HID], sh[HID];                         //  1536 B
  __shared__ float st2[384];                                 //  1536 B => 51200 B total
  const int p  = blockIdx.x;
  const int b  = p >> 6;
  const int fi = (p >> 3) & 7;
  const int fj = p & 7;
  const int t  = threadIdx.x;

  const float inv1 = 1.f / 165888.f;    // 512*324
  for (int c = t; c < HID; c += 256) {
    float m   = sums[c] * inv1;
    float var = sums[192 + c] * inv1 - m * m;
    float scl = g1[c] * rsqrtf(var + EPS);
    sc[c] = scl;
    sh[c] = b1[c] - m * scl;
  }
  for (int i = t; i < 384; i += 256) st2[i] = 0.f;
  {
    const float* wtp = wt2 + (size_t)p * WT2SZ;   // w2 at offset 0, 1728 floats
    for (int i = t; i < HID * 9; i += 256) w2L[i] = wtp[i];
  }

  // stage patch B-frags (identical to k1)
  const int row0 = fi * 16 - 1, col0 = fj * 16 - 1;
  const float* xb = x + (size_t)b * 32 * 128 * 128;
  for (int idx = t; idx < 32 * A1; idx += 256) {
    int c  = idx / A1;
    int ij = idx - c * A1;
    int ii = ij / 18;
    int jj = ij - ii * 18;
    int r  = row0 + ii; r  = (r  < 0) ? 1 : (r  > 127) ? 126 : r;
    int cl = col0 + jj; cl = (cl < 0) ? 1 : (cl > 127) ? 126 : cl;
    int slot = ((ij >> 4) * 4 + (c >> 3)) * 128 + (ij & 15) * 8 + (c & 7);
    pL[slot] = f2bf(xb[((size_t)c * 128 + r) * 128 + cl]);
  }
  __syncthreads();

  const int lane = t & 63;
  const int wv   = t >> 6;
  const int m16  = lane & 15;
  const int quad = lane >> 4;
  // dw coords: t = ih*128 + cdw*8 + jp
  const int ih  = t >> 7;          // 0..1  (i-half)
  const int cdw = (t >> 3) & 15;   // 0..15 (channel within tile)
  const int jp  = t & 7;           // 0..7  (j-pair)
  const unsigned short* wbp = wb1 + (size_t)p * W1SZ;
  unsigned short* x2base = x2 + (size_t)p * 12 * 4096;

  // ---- conv1 for one o-tile rt -> xc[c][ij] (bn1+relu6 applied) ----
  auto conv1 = [&](int rt) {
    bf16x8 a = *(const bf16x8*)(wbp + rt * 512 + lane * 8);
    for (int jt = wv; jt < 21; jt += 4) {
      bf16x8 bb = *(const bf16x8*)&pL[jt * 512 + lane * 8];
      f32x4 d = __builtin_amdgcn_mfma_f32_16x16x32_bf16(a, bb, (f32x4){0.f, 0.f, 0.f, 0.f}, 0, 0, 0);
      const int ij = jt * 16 + m16;
      if (ij < A1) {
#pragma unroll
        for (int r = 0; r < 4; r++) {
          int cl = quad * 4 + r;
          int ch = rt * 16 + cl;
          float v = relu6f(fmaf(d[r], sc[ch], sh[ch]));
          xc[cl * 328 + ij] = f2bf(v);
        }
      }
    }
  };

  conv1(0);
  __syncthreads();

  for (int rt = 0; rt < 12; rt++) {
    // ---- depthwise on tile rt: thread = (ih, cdw, jp); aligned b32 LDS reads ----
    {
      const int ch = rt * 16 + cdw;
      float wr[9];
#pragma unroll
      for (int u = 0; u < 9; u++) wr[u] = w2L[ch * 9 + u];
      float a0[8], a1[8];
#pragma unroll
      for (int i = 0; i < 8; i++) { a0[i] = 0.f; a1[i] = 0.f; }
      const unsigned short* xcc = &xc[cdw * 328];
#pragma unroll
      for (int rr = 0; rr < 10; rr++) {
        const int rg = ih * 8 + rr;
        unsigned int d0 = *(const unsigned int*)&xcc[rg * 18 + jp * 2];
        unsigned int d1 = *(const unsigned int*)&xcc[rg * 18 + jp * 2 + 2];
        float v0 = bf2f(d0 & 0xFFFFu), v1 = bf2f(d0 >> 16);
        float v2 = bf2f(d1 & 0xFFFFu), v3 = bf2f(d1 >> 16);
#pragma unroll
        for (int u = 0; u < 3; u++) {
          int il = rr - u;
          if (il >= 0 && il < 8) {
            a0[il] = fmaf(v0, wr[u * 3 + 0], fmaf(v1, wr[u * 3 + 1], fmaf(v2, wr[u * 3 + 2], a0[il])));
            a1[il] = fmaf(v1, wr[u * 3 + 0], fmaf(v2, wr[u * 3 + 1], fmaf(v3, wr[u * 3 + 2], a1[il])));
          }
        }
      }
      float ls = 0.f, lq = 0.f;
#pragma unroll
      for (int il = 0; il < 8; il++) {
        const int ig = ih * 8 + il;
        const int j0 = jp * 2;
        unsigned short h0 = f2bf(a0[il]);
        unsigned short h1 = f2bf(a1[il]);
        float r0 = bf2f(h0), r1 = bf2f(h1);
        ls += r0 + r1;
        lq = fmaf(r0, r0, fmaf(r1, r1, lq));
        x2s[(ig * 16 + j0) * 18 + cdw]     = h0;
        x2s[(ig * 16 + j0 + 1) * 18 + cdw] = h1;
      }
      // reduce over jp (lanes cdw*8+jp within wave)
      ls += __shfl_xor(ls, 1, 64); lq += __shfl_xor(lq, 1, 64);
      ls += __shfl_xor(ls, 2, 64); lq += __shfl_xor(lq, 2, 64);
      ls += __shfl_xor(ls, 4, 64); lq += __shfl_xor(lq, 4, 64);
      if (jp == 0) {
        atomicAdd(&st2[ch], ls);
        atomicAdd(&st2[192 + ch], lq);
      }
    }
    __syncthreads();
    // ---- coop store x2s -> global [rt][256][16]; overlap conv1 of next tile ----
    {
      unsigned short* dst = x2base + (size_t)rt * 4096;
#pragma unroll
      for (int k = 0; k < 4; k++) {
        int g  = (k * 256 + t) * 4;          // ushort offset, multiple of 4
        int ij = g >> 4, c0 = g & 15;
        unsigned int v0 = *(const unsigned int*)&x2s[ij * 18 + c0];
        unsigned int v1 = *(const unsigned int*)&x2s[ij * 18 + c0 + 2];
        uint2 v; v.x = v0; v.y = v1;
        *(uint2*)&dst[g] = v;
      }
    }
    if (rt < 11) conv1(rt + 1);
    __syncthreads();
  }
  for (int i = t; i < 384; i += 256) atomicAdd(&sums2[i], st2[i]);
}

// ---------------- K3: MFMA pointwise 192->32, bn2+relu6 fused on B-load ----------------
// grid: 1024 = patch(512) * ij-half(2); x3 bf16 [p][o][256]; bn3 stats (on rounded values)
__global__ __launch_bounds__(256) void k3_pw2(const unsigned short* __restrict__ x2,
                                              const float* __restrict__ wt2,
                                              const float* __restrict__ sums2,
                                              const float* __restrict__ g2,
                                              const float* __restrict__ b2,
                                              unsigned short* __restrict__ x3,
                                              float* __restrict__ sums3) {
  __shared__ __align__(16) unsigned short wA[12 * 512];   // A frags: [ot(2)][ks(6)]
  __shared__ float sc[HID], sh[HID];
  __shared__ float st3[64];
  const int blk  = blockIdx.x;
  const int p    = blk >> 1;
  const int half = blk & 1;
  const int t    = threadIdx.x;
  const float inv = 1.f / 131072.f;   // 512*256
  for (int c = t; c < HID; c += 256) {
    float m   = sums2[c] * inv;
    float var = sums2[192 + c] * inv - m * m;
    float scl = g2[c] * rsqrtf(var + EPS);
    sc[c] = scl;
    sh[c] = b2[c] - m * scl;
  }
  if (t < 64) st3[t] = 0.f;
  // stage w3 -> bf16 A-frags: A[m=o&15][k], frag (ot=o>>4, ks=c>>5)
  const float* w3p = wt2 + (size_t)p * WT2SZ + R3OFF;     // [o][192]
  for (int idx = t; idx < 32 * 48; idx += 256) {
    int o  = idx / 48;
    int c4 = idx - o * 48;
    float4 v = *(const float4*)&w3p[o * HID + c4 * 4];
    int slot = ((o >> 4) * 6 + (c4 >> 3)) * 512 + ((((c4 >> 1) & 3) * 16) + (o & 15)) * 8 + (c4 & 1) * 4;
    ushort4 u;
    u.x = f2bf(v.x); u.y = f2bf(v.y); u.z = f2bf(v.z); u.w = f2bf(v.w);
    *(ushort4*)&wA[slot] = u;
  }
  __syncthreads();
  const int lane = t & 63;
  const int wv   = t >> 6;
  const int m16  = lane & 15;
  const int kg   = lane >> 4;
  bf16x8 aF[2][6];
#pragma unroll
  for (int ot = 0; ot < 2; ot++)
#pragma unroll
    for (int ks = 0; ks < 6; ks++)
      aF[ot][ks] = *(const bf16x8*)&wA[(ot * 6 + ks) * 512 + lane * 8];
  const unsigned short* x2p = x2 + (size_t)p * 12 * 4096;
  f32x4 acc[2][2];
#pragma unroll
  for (int it = 0; it < 2; it++)
#pragma unroll
    for (int ot = 0; ot < 2; ot++)
#pragma unroll
      for (int r = 0; r < 4; r++) acc[it][ot][r] = 0.f;
#pragma unroll
  for (int it = 0; it < 2; it++) {
    const int ijt = half * 8 + wv + it * 4;
    const int ij  = ijt * 16 + m16;
    // x2 [ot12][ij][16]: for k = ks*32 + kg*8 + j, addr = ks*8192 + (kg>>1)*4096 + ij*16 + (kg&1)*8
    const unsigned short* brow = x2p + (size_t)(kg >> 1) * 4096 + (size_t)ij * 16 + (kg & 1) * 8;
#pragma unroll
    for (int ks = 0; ks < 6; ks++) {
      ushort4 u0 = *(const ushort4*)&brow[ks * 8192];
      ushort4 u1 = *(const ushort4*)&brow[ks * 8192 + 4];
      const float* scp = &sc[ks * 32 + kg * 8];
      const float* shp = &sh[ks * 32 + kg * 8];
      unsigned short uu[8] = {u0.x, u0.y, u0.z, u0.w, u1.x, u1.y, u1.z, u1.w};
      bf16x8 bb;
#pragma unroll
      for (int j = 0; j < 8; j++) {
        float y = relu6f(fmaf(bf2f(uu[j]), scp[j], shp[j]));
        bb[j] = (short)f2bf(y);
      }
      acc[it][0] = __builtin_amdgcn_mfma_f32_16x16x32_bf16(aF[0][ks], bb, acc[it][0], 0, 0, 0);
      acc[it][1] = __builtin_amdgcn_mfma_f32_16x16x32_bf16(aF[1][ks], bb, acc[it][1], 0, 0, 0);
    }
  }
  unsigned short* x3p = x3 + (size_t)p * 32 * A2;
  float sacc[2][4] = {{0.f}}, qacc[2][4] = {{0.f}};
#pragma unroll
  for (int it = 0; it < 2; it++) {
    const int ijt = half * 8 + wv + it * 4;
#pragma unroll
    for (int ot = 0; ot < 2; ot++) {
#pragma unroll
      for (int r = 0; r < 4; r++) {
        unsigned short h = f2bf(acc[it][ot][r]);
        float v = bf2f(h);
        x3p[(size_t)(ot * 16 + kg * 4 + r) * A2 + ijt * 16 + m16] = h;
        sacc[ot][r] += v;
        qacc[ot][r] = fmaf(v, v, qacc[ot][r]);
      }
    }
  }
#pragma unroll
  for (int ot = 0; ot < 2; ot++)
#pragma unroll
    for (int r = 0; r < 4; r++) {
      float sv = sacc[ot][r], qv = qacc[ot][r];
#pragma unroll
      for (int msk = 1; msk < 16; msk <<= 1) {
        sv += __shfl_xor(sv, msk, 64);
        qv += __shfl_xor(qv, msk, 64);
      }
      if (m16 == 0) {
        int o = ot * 16 + kg * 4 + r;
        atomicAdd(&st3[o], sv);
        atomicAdd(&st3[32 + o], qv);
      }
    }
  __syncthreads();
  if (t < 64) atomicAdd(&sums3[t], st3[t]);
}

// ---------------- K4: bn3 + residual + layout transform ----------------
__global__ __launch_bounds__(256) void k4_out(const float* __restrict__ x,
                                              const unsigned short* __restrict__ x3,
                                              const float* __restrict__ sums3,
                                              const float* __restrict__ g3,
                                              const float* __restrict__ b3,
                                              float* __restrict__ out) {
  const int idx4 = blockIdx.x * 256 + threadIdx.x;   // 1,048,576 float4 total
  const int w4 = idx4 & 31;
  int tmp = idx4 >> 5;
  const int h = tmp & 127; tmp >>= 7;
  const int o = tmp & 31;
  const int b = tmp >> 5;
  const int fi = h >> 4, i = h & 15;
  const int fj = w4 >> 2;
  const int j0 = (w4 & 3) * 4;
  const int p   = b * 64 + fi * 8 + fj;
  const int ij0 = i * 16 + j0;
  const float inv = 1.f / 131072.f;
  float m   = sums3[o] * inv;
  float var = sums3[32 + o] * inv - m * m;
  float sv  = g3[o] * rsqrtf(var + EPS);
  float shv = b3[o] - m * sv;
  float4 xv = *(const float4*)&x[(size_t)idx4 * 4];
  ushort4 u = *(const ushort4*)&x3[((size_t)p * 32 + o) * A2 + ij0];
  float4 r;
  r.x = fmaf(bf2f(u.x), sv, shv) + xv.x;
  r.y = fmaf(bf2f(u.y), sv, shv) + xv.y;
  r.z = fmaf(bf2f(u.z), sv, shv) + xv.z;
  r.w = fmaf(bf2f(u.w), sv, shv) + xv.w;
  *(float4*)&out[(size_t)idx4 * 4] = r;
}

extern "C" void kernel_launch(void* const* d_in, const int* in_sizes, int n_in,
                              void* d_out, int out_size, void* d_ws, size_t ws_size,
                              hipStream_t stream) {
  const float* x  = (const float*)d_in[0];
  const float* s  = (const float*)d_in[1];
  const float* g1 = (const float*)d_in[2];
  const float* b1 = (const float*)d_in[3];
  const float* g2 = (const float*)d_in[4];
  const float* b2 = (const float*)d_in[5];
  const float* g3 = (const float*)d_in[6];
  const float* b3 = (const float*)d_in[7];
  char* base = (char*)d_ws;
  unsigned short* wb1  = (unsigned short*)(base + WB1_B);
  float*          wt2  = (float*)(base + WT2_B);
  unsigned short* x2   = (unsigned short*)(base + X2_B);
  unsigned short* x3   = (unsigned short*)(base + X3_B);
  float*          sums = (float*)(base + SUM_B);
  float* out = (float*)d_out;

  hipMemsetAsync(sums, 0, 832 * sizeof(float), stream);
  k0_transpose<<<8 * 219, 256, 0, stream>>>(s, wb1, wt2);
  k1_stats<<<P_TOT, 256, 0, stream>>>(x, wb1, sums);
  k2_fused<<<P_TOT, 256, 0, stream>>>(x, wb1, wt2, sums, g1, b1, x2, sums + 384);
  k3_pw2<<<1024, 256, 0, stream>>>(x2, wt2, sums + 384, g2, b2, x3, sums + 768);
  k4_out<<<4096, 256, 0, stream>>>(x, x3, sums + 768, g3, b3, out);
}